// Round 1
// 507.562 us; speedup vs baseline: 1.0001x; 1.0001x over previous
//
#include <hip/hip_runtime.h>

// ---------------------------------------------------------------------------
// T5-style self-attention, MI355X (gfx950), fp16 MFMA internal precision.
// B=2, S=2048, H=16, DK=64, D_MODEL=1024.
// R4 = R3 +
//   (a) qkv/out GEMMs: global_load_lds width=16 staging, linear LDS (m97
//       structure; 16-way ds_read conflicts accepted — measured net win).
//   (b) attn: T14 async-STAGE split — issue K/V/bias global loads for kt+1
//       into regs BEFORE compute(kt), ds_write AFTER the post-compute barrier
//       (m214 v27: +17% on attn).
//   (c) 5 cvt launches fused into 1.
// ---------------------------------------------------------------------------

typedef _Float16 f16_t;
typedef _Float16 f16x8 __attribute__((ext_vector_type(8)));
typedef _Float16 f16x4 __attribute__((ext_vector_type(4)));
typedef _Float16 f16x2 __attribute__((ext_vector_type(2)));
typedef float   floatx4 __attribute__((ext_vector_type(4)));

#define MFMA16(a, b, c)    __builtin_amdgcn_mfma_f32_16x16x32_f16((a), (b), (c), 0, 0, 0)
#define MFMA16K16(a, b, c) __builtin_amdgcn_mfma_f32_16x16x16f16((a), (b), (c), 0, 0, 0)

__device__ __forceinline__ void gload_lds16(const f16_t* g, f16_t* l) {
  __builtin_amdgcn_global_load_lds(
      (const __attribute__((address_space(1))) void*)g,
      (__attribute__((address_space(3))) void*)l, 16, 0, 0);
}

// ---------------- fused fp32 -> fp16 convert (x + 4 weights, 1 launch) -----
__global__ __launch_bounds__(256) void cvt_all(
    const float* __restrict__ x,  const float* __restrict__ wq,
    const float* __restrict__ wk, const float* __restrict__ wv,
    const float* __restrict__ wo,
    f16_t* __restrict__ xb,  f16_t* __restrict__ wqb, f16_t* __restrict__ wkb,
    f16_t* __restrict__ wvb, f16_t* __restrict__ wob) {
  int b = blockIdx.x;
  const float* src; f16_t* dst; int base;
  if (b < 4096)      { src = x;  dst = xb;  base = b; }
  else if (b < 5120) { src = wq; dst = wqb; base = b - 4096; }
  else if (b < 6144) { src = wk; dst = wkb; base = b - 5120; }
  else if (b < 7168) { src = wv; dst = wvb; base = b - 6144; }
  else               { src = wo; dst = wob; base = b - 7168; }
  int i = (base * 256 + threadIdx.x) * 4;
  floatx4 v = *(const floatx4*)(src + i);
  f16x4 o;
  o.x = (_Float16)v.x; o.y = (_Float16)v.y; o.z = (_Float16)v.z; o.w = (_Float16)v.w;
  *(f16x4*)(dst + i) = o;
}

// ---------------- fused QKV projection: 128x128 tile, global_load_lds ------
// A = x [4096,1024] f16, B = w [1024,1024] f16 (row-major [n][k]).
// grid (32, 24); by>>3 selects w_q/w_k/w_v; (by&7)*128 = feature base.
// Output: q/k/v [B=2][H=16][S=2048][DK=64] f16.
// LDS is LINEAR [128][64] (global_load_lds requires contiguous dest).
__global__ __launch_bounds__(256) void qkv_gemm(
    const f16_t* __restrict__ xb,
    const f16_t* __restrict__ wqb, const f16_t* __restrict__ wkb,
    const f16_t* __restrict__ wvb,
    f16_t* __restrict__ qb, f16_t* __restrict__ kb, f16_t* __restrict__ vb) {
  __shared__ f16_t As[128 * 64];
  __shared__ f16_t Bs[128 * 64];
  const int t = threadIdx.x;
  const int w = t >> 6, lane = t & 63, quad = lane >> 4, col = lane & 15;
  const int wm = w & 1, wn = w >> 1;
  const int mbase = blockIdx.x * 128;
  const int which = blockIdx.y >> 3;
  const int ncol0 = (blockIdx.y & 7) * 128;
  const f16_t* wsel = (which == 0) ? wqb : (which == 1) ? wkb : wvb;
  f16_t* osel = (which == 0) ? qb : (which == 1) ? kb : vb;

  floatx4 zero4 = {0.f, 0.f, 0.f, 0.f};
  floatx4 acc[4][4];
#pragma unroll
  for (int i = 0; i < 4; ++i)
#pragma unroll
    for (int j = 0; j < 4; ++j) acc[i][j] = zero4;

  for (int kt = 0; kt < 16; ++kt) {
    const int k0 = kt * 64;
#pragma unroll
    for (int rep = 0; rep < 4; ++rep) {
      // chunk = rep*256 + w*64 + lane; 16B per lane; LDS base wave-uniform.
      int chunk = rep * 256 + w * 64 + lane;
      int r = chunk >> 3, c8 = (chunk & 7) * 8;
      f16_t* abase = As + (size_t)(rep * 256 + w * 64) * 8;
      f16_t* bbase = Bs + (size_t)(rep * 256 + w * 64) * 8;
      gload_lds16(xb + (size_t)(mbase + r) * 1024 + k0 + c8, abase);
      gload_lds16(wsel + (size_t)(ncol0 + r) * 1024 + k0 + c8, bbase);
    }
    __syncthreads();
#pragma unroll
    for (int ch = 0; ch < 2; ++ch) {
      f16x8 a[4], b[4];
#pragma unroll
      for (int i = 0; i < 4; ++i)
        a[i] = *(const f16x8*)(As + (size_t)(wm * 64 + i * 16 + col) * 64 + ch * 32 + quad * 8);
#pragma unroll
      for (int j = 0; j < 4; ++j)
        b[j] = *(const f16x8*)(Bs + (size_t)(wn * 64 + j * 16 + col) * 64 + ch * 32 + quad * 8);
#pragma unroll
      for (int i = 0; i < 4; ++i)
#pragma unroll
        for (int j = 0; j < 4; ++j)
          acc[i][j] = MFMA16(a[i], b[j], acc[i][j]);
    }
    __syncthreads();
  }
  // epilogue: C row=quad*4+rr (M), col=lane&15 (N); scatter to head layout
#pragma unroll
  for (int i = 0; i < 4; ++i)
#pragma unroll
    for (int j = 0; j < 4; ++j)
#pragma unroll
      for (int rr = 0; rr < 4; ++rr) {
        int m = mbase + wm * 64 + i * 16 + quad * 4 + rr;  // token b*2048+s
        int nf = ncol0 + wn * 64 + j * 16 + col;           // feature 0..1023
        int h = nf >> 6, d = nf & 63;
        int bb2 = m >> 11, s = m & 2047;
        osel[(size_t)(((bb2 * 16 + h) * 2048) + s) * 64 + d] = (f16_t)acc[i][j][rr];
      }
}

// ---------------- output projection: 128x128 tile, global_load_lds ---------
__global__ __launch_bounds__(256) void out_gemm(
    const f16_t* __restrict__ ab, const f16_t* __restrict__ wob,
    float* __restrict__ outp) {
  __shared__ f16_t As[128 * 64];
  __shared__ f16_t Bs[128 * 64];
  const int t = threadIdx.x;
  const int w = t >> 6, lane = t & 63, quad = lane >> 4, col = lane & 15;
  const int wm = w & 1, wn = w >> 1;
  const int mbase = blockIdx.x * 128;
  const int nbase = blockIdx.y * 128;

  floatx4 zero4 = {0.f, 0.f, 0.f, 0.f};
  floatx4 acc[4][4];
#pragma unroll
  for (int i = 0; i < 4; ++i)
#pragma unroll
    for (int j = 0; j < 4; ++j) acc[i][j] = zero4;

  for (int kt = 0; kt < 16; ++kt) {
    const int k0 = kt * 64;
#pragma unroll
    for (int rep = 0; rep < 4; ++rep) {
      int chunk = rep * 256 + w * 64 + lane;
      int r = chunk >> 3, c8 = (chunk & 7) * 8;
      f16_t* abase = As + (size_t)(rep * 256 + w * 64) * 8;
      f16_t* bbase = Bs + (size_t)(rep * 256 + w * 64) * 8;
      gload_lds16(ab + (size_t)(mbase + r) * 1024 + k0 + c8, abase);
      gload_lds16(wob + (size_t)(nbase + r) * 1024 + k0 + c8, bbase);
    }
    __syncthreads();
#pragma unroll
    for (int ch = 0; ch < 2; ++ch) {
      f16x8 a[4], b[4];
#pragma unroll
      for (int i = 0; i < 4; ++i)
        a[i] = *(const f16x8*)(As + (size_t)(wm * 64 + i * 16 + col) * 64 + ch * 32 + quad * 8);
#pragma unroll
      for (int j = 0; j < 4; ++j)
        b[j] = *(const f16x8*)(Bs + (size_t)(wn * 64 + j * 16 + col) * 64 + ch * 32 + quad * 8);
#pragma unroll
      for (int i = 0; i < 4; ++i)
#pragma unroll
        for (int j = 0; j < 4; ++j)
          acc[i][j] = MFMA16(a[i], b[j], acc[i][j]);
    }
    __syncthreads();
  }
#pragma unroll
  for (int i = 0; i < 4; ++i)
#pragma unroll
    for (int j = 0; j < 4; ++j)
#pragma unroll
      for (int rr = 0; rr < 4; ++rr) {
        int m = mbase + wm * 64 + i * 16 + quad * 4 + rr;
        int n = nbase + wn * 64 + j * 16 + col;
        outp[(size_t)m * 1024 + n] = acc[i][j][rr];
      }
}

// ---------------- flash attention, S^T formulation + T14 async-STAGE -------
// grid (32 qtiles, 16 heads), 512 threads = 8 waves.
// waves 0-3: batch 0; waves 4-7: batch 1. Bias tile staged once, shared.
// Pipeline: issue global loads for tile kt+1 into regs, compute tile kt from
// LDS, barrier, ds_write the staged regs, barrier.  HBM latency of the bias
// stream (the hard floor) hides under the MFMA+softmax of the current tile.
__global__ __launch_bounds__(512) void attn_kernel(
    const f16_t* __restrict__ qb, const f16_t* __restrict__ kb,
    const f16_t* __restrict__ vb, const float* __restrict__ bias,
    f16_t* __restrict__ ctxb) {
  __shared__ f16_t Ks[2][64][72];    // [batch][key][d]       (18.4 KB)
  __shared__ f16_t Vt[2][64][76];    // [batch][d][key] pad76 (19.5 KB)
  __shared__ f16_t biasS[64][72];    // [q_local][k_local]    ( 9.2 KB)

  const int t = threadIdx.x;
  const int w = t >> 6, lane = t & 63, quad = lane >> 4, col = lane & 15;
  const int bb = w >> 2, w4 = w & 3;
  const int h = blockIdx.y;
  const int qbase = blockIdx.x * 64;

  // staging decomposition (loop-invariant)
  const int vb2 = t >> 8, vrem = t & 255;
  const int vk0 = (vrem & 31) * 2, vd0 = (vrem >> 5) * 8;   // 2 k-rows, 8 d
  const int br = t >> 3, bc0 = (t & 7) * 8;                 // bias row/col

  // Q fragments (B-operand: n=lane&15=q, k=quad*8+j=d)
  f16x8 qf[2];
  {
    const f16_t* qp = qb + (size_t)(((bb * 16 + h) * 2048) + qbase + w4 * 16 + col) * 64;
    qf[0] = *(const f16x8*)(qp + quad * 8);
    qf[1] = *(const f16x8*)(qp + 32 + quad * 8);
  }

  float mprev = -3e38f, lrun = 0.f;   // per-lane: row q = w4*16 + col
  floatx4 zero4 = {0.f, 0.f, 0.f, 0.f};
  floatx4 oacc[4];
  oacc[0] = oacc[1] = oacc[2] = oacc[3] = zero4;

  // ---- prologue: stage tile kt=0 synchronously ----
  {
#pragma unroll
    for (int rep = 0; rep < 2; ++rep) {
      int cid = t + rep * 512;
      int b2 = cid >> 9, rem = cid & 511;
      int r = rem >> 3, c = (rem & 7) * 8;
      *(f16x8*)&Ks[b2][r][c] =
          *(const f16x8*)(kb + (size_t)(((b2 * 16 + h) * 2048) + r) * 64 + c);
    }
    f16x8 r0 = *(const f16x8*)(vb + (size_t)(((vb2 * 16 + h) * 2048) + vk0) * 64 + vd0);
    f16x8 r1 = *(const f16x8*)(vb + (size_t)(((vb2 * 16 + h) * 2048) + vk0 + 1) * 64 + vd0);
#pragma unroll
    for (int d = 0; d < 8; ++d) {
      f16x2 pk; pk.x = r0[d]; pk.y = r1[d];
      *(f16x2*)&Vt[vb2][vd0 + d][vk0] = pk;
    }
    const float* bp = bias + ((size_t)h * 2048 + qbase + br) * 2048 + bc0;
    floatx4 v0 = *(const floatx4*)bp;
    floatx4 v1 = *(const floatx4*)(bp + 4);
    f16x8 bo;
    bo[0] = (_Float16)v0.x; bo[1] = (_Float16)v0.y;
    bo[2] = (_Float16)v0.z; bo[3] = (_Float16)v0.w;
    bo[4] = (_Float16)v1.x; bo[5] = (_Float16)v1.y;
    bo[6] = (_Float16)v1.z; bo[7] = (_Float16)v1.w;
    *(f16x8*)&biasS[br][bc0] = bo;
  }
  __syncthreads();

  f16x8 kreg0, kreg1, vreg0, vreg1;
  floatx4 breg0, breg1;

  for (int kt = 0; kt < 32; ++kt) {
    // ---- T14 issue phase: global loads for tile kt+1 (async, no wait) ----
    if (kt < 31) {
      const int nb = (kt + 1) * 64;
      {
        int cid = t;
        int b2 = cid >> 9, rem = cid & 511, r = rem >> 3, c = (rem & 7) * 8;
        kreg0 = *(const f16x8*)(kb + (size_t)(((b2 * 16 + h) * 2048) + nb + r) * 64 + c);
        cid = t + 512;
        b2 = cid >> 9; rem = cid & 511; r = rem >> 3; c = (rem & 7) * 8;
        kreg1 = *(const f16x8*)(kb + (size_t)(((b2 * 16 + h) * 2048) + nb + r) * 64 + c);
      }
      vreg0 = *(const f16x8*)(vb + (size_t)(((vb2 * 16 + h) * 2048) + nb + vk0) * 64 + vd0);
      vreg1 = *(const f16x8*)(vb + (size_t)(((vb2 * 16 + h) * 2048) + nb + vk0 + 1) * 64 + vd0);
      const float* bp = bias + ((size_t)h * 2048 + qbase + br) * 2048 + nb + bc0;
      breg0 = *(const floatx4*)bp;
      breg1 = *(const floatx4*)(bp + 4);
    }

    // ---- S^T = K Q^T : 16 keys per cb tile, this wave's 16 q-rows ----
    floatx4 sacc[4];
    sacc[0] = sacc[1] = sacc[2] = sacc[3] = zero4;
#pragma unroll
    for (int ch = 0; ch < 2; ++ch) {
#pragma unroll
      for (int cb = 0; cb < 4; ++cb) {
        f16x8 kf = *(const f16x8*)&Ks[bb][cb * 16 + col][ch * 32 + quad * 8];
        sacc[cb] = MFMA16(kf, qf[ch], sacc[cb]);
      }
    }
    // ---- bias add: lane's q-row = w4*16+col, keys cb*16+quad*4+i ----
    float sv[4][4];
#pragma unroll
    for (int cb = 0; cb < 4; ++cb) {
      f16x4 b4 = *(const f16x4*)&biasS[w4 * 16 + col][cb * 16 + quad * 4];
#pragma unroll
      for (int i = 0; i < 4; ++i)
        sv[cb][i] = sacc[cb][i] + (float)b4[i];
    }
    // ---- per-lane softmax over 16 keys; cross-quad reduce (2 shfl) ----
    float rm = -3e38f;
#pragma unroll
    for (int cb = 0; cb < 4; ++cb)
#pragma unroll
      for (int i = 0; i < 4; ++i) rm = fmaxf(rm, sv[cb][i]);
    rm = fmaxf(rm, __shfl_xor(rm, 16, 64));
    rm = fmaxf(rm, __shfl_xor(rm, 32, 64));
    float mnew = fmaxf(mprev, rm);
    float alpha = __expf(mprev - mnew);
    mprev = mnew;
    float ls = 0.f;
#pragma unroll
    for (int cb = 0; cb < 4; ++cb)
#pragma unroll
      for (int i = 0; i < 4; ++i) {
        float p = __expf(sv[cb][i] - mnew);
        sv[cb][i] = p;
        ls += p;
      }
    lrun = lrun * alpha + ls;
    // ---- rescale O: alpha for O-rows quad*4+i (4 broadcasts) ----
    float a0 = __shfl(alpha, quad * 4 + 0, 64);
    float a1 = __shfl(alpha, quad * 4 + 1, 64);
    float a2 = __shfl(alpha, quad * 4 + 2, 64);
    float a3 = __shfl(alpha, quad * 4 + 3, 64);
#pragma unroll
    for (int db = 0; db < 4; ++db) {
      oacc[db].x *= a0; oacc[db].y *= a1; oacc[db].z *= a2; oacc[db].w *= a3;
    }
    // ---- O += P V : P direct from regs (A-operand), V from Vt (B) ----
#pragma unroll
    for (int cb = 0; cb < 4; ++cb) {
      f16x4 pf;
      pf[0] = (_Float16)sv[cb][0]; pf[1] = (_Float16)sv[cb][1];
      pf[2] = (_Float16)sv[cb][2]; pf[3] = (_Float16)sv[cb][3];
#pragma unroll
      for (int db = 0; db < 4; ++db) {
        f16x4 vf = *(const f16x4*)&Vt[bb][db * 16 + col][cb * 16 + quad * 4];
        oacc[db] = MFMA16K16(pf, vf, oacc[db]);
      }
    }
    __syncthreads();   // all waves done READING Ks/Vt/biasS for tile kt

    // ---- T14 write phase: staged regs -> LDS (waitcnt lands here) ----
    if (kt < 31) {
      {
        int cid = t;
        int b2 = cid >> 9, rem = cid & 511, r = rem >> 3, c = (rem & 7) * 8;
        *(f16x8*)&Ks[b2][r][c] = kreg0;
        cid = t + 512;
        b2 = cid >> 9; rem = cid & 511; r = rem >> 3; c = (rem & 7) * 8;
        *(f16x8*)&Ks[b2][r][c] = kreg1;
      }
#pragma unroll
      for (int d = 0; d < 8; ++d) {
        f16x2 pk; pk.x = vreg0[d]; pk.y = vreg1[d];
        *(f16x2*)&Vt[vb2][vd0 + d][vk0] = pk;
      }
      f16x8 bo;
      bo[0] = (_Float16)breg0.x; bo[1] = (_Float16)breg0.y;
      bo[2] = (_Float16)breg0.z; bo[3] = (_Float16)breg0.w;
      bo[4] = (_Float16)breg1.x; bo[5] = (_Float16)breg1.y;
      bo[6] = (_Float16)breg1.z; bo[7] = (_Float16)breg1.w;
      *(f16x8*)&biasS[br][bc0] = bo;
      __syncthreads();   // tile kt+1 visible
    }
  }

  // ---- finalize: total row sums (2 shfl), then divide & store ----
  float lt = lrun;
  lt += __shfl_xor(lt, 16, 64);
  lt += __shfl_xor(lt, 32, 64);
  float linv[4];
#pragma unroll
  for (int i = 0; i < 4; ++i)
    linv[i] = 1.0f / __shfl(lt, quad * 4 + i, 64);
#pragma unroll
  for (int db = 0; db < 4; ++db)
#pragma unroll
    for (int i = 0; i < 4; ++i) {
      int m = bb * 2048 + qbase + w4 * 16 + quad * 4 + i;
      int n = h * 64 + db * 16 + col;
      ctxb[(size_t)m * 1024 + n] = (f16_t)(oacc[db][i] * linv[i]);
    }
}

// ---------------------------------------------------------------------------
extern "C" void kernel_launch(void* const* d_in, const int* in_sizes, int n_in,
                              void* d_out, int out_size, void* d_ws, size_t ws_size,
                              hipStream_t stream) {
  const float* x    = (const float*)d_in[0];
  const float* bias = (const float*)d_in[1];
  const float* wq   = (const float*)d_in[2];
  const float* wk   = (const float*)d_in[3];
  const float* wv   = (const float*)d_in[4];
  const float* wo   = (const float*)d_in[5];
  float* outp = (float*)d_out;
  char* ws = (char*)d_ws;
  const size_t MB = 1u << 20;

  f16_t* xb   = (f16_t*)(ws);             //  8 MB
  f16_t* wqb  = (f16_t*)(ws + 8 * MB);    //  2 MB
  f16_t* wkb  = (f16_t*)(ws + 10 * MB);   //  2 MB
  f16_t* wvb  = (f16_t*)(ws + 12 * MB);   //  2 MB
  f16_t* wob  = (f16_t*)(ws + 14 * MB);   //  2 MB
  f16_t* qb   = (f16_t*)(ws + 16 * MB);   //  8 MB [2,16,2048,64]
  f16_t* kb   = (f16_t*)(ws + 24 * MB);   //  8 MB
  f16_t* vb   = (f16_t*)(ws + 32 * MB);   //  8 MB
  f16_t* ctxb = (f16_t*)(ws + 40 * MB);   //  8 MB [4096,1024]

  cvt_all<<<8192, 256, 0, stream>>>(x, wq, wk, wv, wo, xb, wqb, wkb, wvb, wob);
  qkv_gemm<<<dim3(32, 24), 256, 0, stream>>>(xb, wqb, wkb, wvb, qb, kb, vb);
  attn_kernel<<<dim3(32, 16), 512, 0, stream>>>(qb, kb, vb, bias, ctxb);
  out_gemm<<<dim3(32, 8), 256, 0, stream>>>(ctxb, wob, outp);
}